// Round 12
// baseline (4052.472 us; speedup 1.0000x reference)
//
#include <hip/hip_runtime.h>
#include <hip/hip_bf16.h>
#include <stdint.h>

typedef __attribute__((ext_vector_type(8))) short short8;
typedef __attribute__((ext_vector_type(4))) float floatx4;
typedef __attribute__((ext_vector_type(4))) unsigned int uintx4;
typedef __attribute__((ext_vector_type(4))) unsigned short ushort4v;

#define DEVI __device__ __forceinline__

// ---- problem sizes ----
constexpr int B_ = 256, T_ = 512, D_ = 128, H_ = 512, C_ = 10;
constexpr int KTOT = H_ + D_;       // 640: k = [h(512) ; x(128)]
constexpr int RG = 16;              // batch rows per group
constexpr int NBG = 16;             // batch groups
constexpr int NCG = 16;             // column groups
constexpr int HCW = 32;             // h-cols per WG

// ---- workspace layout (bytes) ----
constexpr size_t OFF_XB = 0;
constexpr size_t SZ_XB  = (size_t)B_ * T_ * D_ * 2;          // x in bf16
constexpr size_t OFF_WC = OFF_XB + SZ_XB;
constexpr size_t SZ_WC  = (size_t)4 * H_ * KTOT * 2;         // Wcomb[4*H][640] bf16
constexpr size_t OFF_HB = OFF_WC + SZ_WC;
constexpr size_t SZ_HB  = (size_t)2 * B_ * H_ * 2;           // h double buffer bf16
constexpr size_t OFF_FL = OFF_HB + SZ_HB;
constexpr size_t SZ_FL  = (size_t)NBG * NCG * 64;            // flags: 64B apart
constexpr size_t WS_NEED = OFF_FL + SZ_FL;

DEVI uint16_t f2bf(float f) {
    uint32_t u = __builtin_bit_cast(uint32_t, f);
    u += 0x7FFFu + ((u >> 16) & 1u);
    return (uint16_t)(u >> 16);
}
DEVI float bf2f(uint16_t u) {
    return __builtin_bit_cast(float, (uint32_t)u << 16);
}
DEVI float sigf(float x)  { return 1.0f / (1.0f + __expf(-x)); }
DEVI float tanhf_(float x){ return 1.0f - 2.0f / (1.0f + __expf(2.0f * x)); }

// ---- prep: x fp32 -> bf16 ----
__global__ void k_cvt_x(const float* __restrict__ x, uint16_t* __restrict__ xb) {
    int i = (blockIdx.x * 256 + threadIdx.x) * 4;   // total B*T*D = 16777216
    float4 v = *reinterpret_cast<const float4*>(x + i);
    ushort4v o;
    o.x = f2bf(v.x); o.y = f2bf(v.y); o.z = f2bf(v.z); o.w = f2bf(v.w);
    *reinterpret_cast<ushort4v*>(xb + i) = o;
}

// ---- prep: build combined transposed bf16 weights Wcomb[n'=g*512+n][k] ----
__global__ void k_build_w(const float* __restrict__ wgh, const float* __restrict__ wih,
                          const float* __restrict__ wfh, const float* __restrict__ woh,
                          const float* __restrict__ wgx, const float* __restrict__ wix,
                          const float* __restrict__ wfx, const float* __restrict__ wox,
                          uint16_t* __restrict__ wc) {
    int np = blockIdx.x;            // 0..2047
    int g = np >> 9, n = np & 511;
    const float* wh = (g == 0) ? wgh : (g == 1) ? wih : (g == 2) ? wfh : woh;
    const float* wx = (g == 0) ? wgx : (g == 1) ? wix : (g == 2) ? wfx : wox;
    for (int k = threadIdx.x; k < KTOT; k += 256) {
        float v = (k < H_) ? wh[(size_t)k * H_ + n] : wx[(size_t)(k - H_) * H_ + n];
        wc[(size_t)np * KTOT + k] = f2bf(v);
    }
}

// Opaque 16B weight load (kept resident in the unified VGPR/AGPR file)
#define WLOAD(dst, base, IMM) \
    asm volatile("global_load_dwordx4 %0, %1, off offset:" #IMM \
                 : "=v"(dst) : "v"(base))
#define WLOAD20(arr, base) \
    WLOAD(arr[0],  base, 0);    WLOAD(arr[1],  base, 64);   \
    WLOAD(arr[2],  base, 128);  WLOAD(arr[3],  base, 192);  \
    WLOAD(arr[4],  base, 256);  WLOAD(arr[5],  base, 320);  \
    WLOAD(arr[6],  base, 384);  WLOAD(arr[7],  base, 448);  \
    WLOAD(arr[8],  base, 512);  WLOAD(arr[9],  base, 576);  \
    WLOAD(arr[10], base, 640);  WLOAD(arr[11], base, 704);  \
    WLOAD(arr[12], base, 768);  WLOAD(arr[13], base, 832);  \
    WLOAD(arr[14], base, 896);  WLOAD(arr[15], base, 960);  \
    WLOAD(arr[16], base, 1024); WLOAD(arr[17], base, 1088); \
    WLOAD(arr[18], base, 1152); WLOAD(arr[19], base, 1216)

// ---- main recurrent kernel ----
// WG = 16 batch rows x 32 h-cols (4 waves, one gate per wave; pre[] LDS gate
// exchange -- r8-proven structure). Sync per step (r8-proven semantics):
//   producer: h store (sc1, relaxed) -> vmcnt(0) drain -> barrier -> tid0 flag
//   consumer: wave0 polls the 16 per-cg flags in parallel (+ballot), barrier,
//             then ACQUIRE FENCE (agent) once, then CACHED h loads.
// The fence invalidates the XCD's L1/L2 once per step, so the 16 WGs of a
// batch-group (same XCD via swizzle) SHARE one L2 fill of the h tile instead
// of each re-reading it at the device coherence point (16x MALL read cut).
// Freshness: hbuf lines enter L2 only via loads issued after all flags(t)
// posted, and flags post only after producers drained to MALL.
__global__ __launch_bounds__(256, 1) void k_lstm(
    const uint16_t* __restrict__ xb,   // [B][T][D] bf16
    const uint16_t* __restrict__ wc,   // [4H][KTOT] bf16
    const float* __restrict__ bgp, const float* __restrict__ bip,
    const float* __restrict__ bfp, const float* __restrict__ bop,
    uint16_t* hbuf,                    // [2][B][H] bf16
    int* flags)                        // [NBG][NCG] ints, 64B apart
{
    __shared__ __align__(16) char hx[RG * KTOT * 2];              // 20 KB, XOR-swizzled
    __shared__ float pre[4][RG][HCW + 1];                         // stride 33

    const int tid  = threadIdx.x;
    const int lane = tid & 63;
    const int w    = tid >> 6;          // wave id == gate id (g,i,f,o)
    const int bid  = blockIdx.x;
    // keep each batch-group's 16 WGs on one XCD (required for the L2-sharing
    // SPEED win; correctness holds regardless of mapping)
    const int xcd = bid & 7, j = bid >> 3;
    const int bg = xcd * 2 + (j >> 4);
    const int cg = j & 15;
    const int b0  = bg * RG;
    const int hc0 = cg * HCW;

    // ---- load this wave's weight slice into registers (resident all run) ----
    short8 bfr0[20], bfr1[20];
    {
        const int lcol = lane & 15, kgrp = lane >> 4;
        const uint16_t* src0 = wc + (size_t)(w * H_ + hc0 + 0  + lcol) * KTOT + kgrp * 8;
        const uint16_t* src1 = wc + (size_t)(w * H_ + hc0 + 16 + lcol) * KTOT + kgrp * 8;
        WLOAD20(bfr0, src0);
        WLOAD20(bfr1, src1);
        asm volatile("s_waitcnt vmcnt(0)" ::: "memory");
    }

    // ---- elementwise thread mapping: (row, col pair) fixed for whole run ----
    const int erow = tid >> 4;          // 0..15
    const int epr  = tid & 15;          // 0..15 -> cols epr*2, epr*2+1
    const int hcg0 = hc0 + epr * 2;
    float bge[2], bie[2], bfe[2], boe[2], cst[2] = {0.f, 0.f};
    #pragma unroll
    for (int e = 0; e < 2; ++e) {
        bge[e] = bgp[hcg0 + e]; bie[e] = bip[hcg0 + e];
        bfe[e] = bfp[hcg0 + e]; boe[e] = bop[hcg0 + e];
    }

    // staging mapping: thread -> (row, 64B segment)
    const int srow = tid >> 4, sseg = tid & 15;
    const int sswz = (srow & 7) << 4;
    // A-fragment base (mfma 16x16x32: row = lane&15, k = (lane>>4)*8 + j)
    const int arow = lane & 15, akg = lane >> 4;
    const int abase = arow * (KTOT * 2) + akg * 16;
    const int aswz  = (arow & 7) << 4;

    int* fbase = flags + bg * NCG * 16;   // 16 ints (=64B) per flag slot
    char* lds = (char*)hx;

    for (int t = 0; t < T_; ++t) {
        // ---- stage x part (cols 512..639) BEFORE the wait (no h dependence;
        //      prev step's LDS readers passed the post-store barrier) ----
        {
            const short8 xv = *reinterpret_cast<const short8*>(
                xb + ((size_t)(b0 + srow) * T_ + t) * D_ + sseg * 8);
            int byte = srow * (KTOT * 2) + H_ * 2 + sseg * 16;
            *reinterpret_cast<short8*>(lds + (byte ^ sswz)) = xv;
        }

        // ---- wait for h_t from all 16 column groups (parallel flag poll) ----
        if (t > 0) {
            if (w == 0) {
                int it = 0;
                for (;;) {
                    int f = t;
                    if (lane < NCG)
                        f = __hip_atomic_load(fbase + lane * 16, __ATOMIC_RELAXED,
                                              __HIP_MEMORY_SCOPE_AGENT);
                    if (__ballot(f >= t) == ~0ull) break;
                    if (++it > (1 << 22)) break;   // fail loud, not hang
                }
                asm volatile("" ::: "memory");
            }
            __syncthreads();
            // ONE acquire fence per step: invalidate L1/L2 so the cached h
            // loads below observe the producers' MALL-resident h(t). NOT in
            // the poll loop (round-1 pathology) -- once per step is cheap.
            __builtin_amdgcn_fence(__ATOMIC_ACQUIRE, "agent");
        }

        // ---- stage h part of A = [h_t ; x_t] into swizzled LDS ----
        if (t == 0) {
            uintx4 z = {0u, 0u, 0u, 0u};
            #pragma unroll
            for (int c4 = 0; c4 < 4; ++c4) {
                int byte = srow * (KTOT * 2) + sseg * 64 + c4 * 16;
                *reinterpret_cast<uintx4*>(lds + (byte ^ sswz)) = z;
            }
        } else {
            // CACHED loads: first toucher fills the XCD L2; the other WGs of
            // this batch-group hit L2 instead of going to the MALL.
            const uintx4* src = reinterpret_cast<const uintx4*>(
                hbuf + (size_t)(t & 1) * B_ * H_ + (size_t)(b0 + srow) * H_ + sseg * 32);
            uintx4 v0 = src[0], v1 = src[1], v2 = src[2], v3 = src[3];
            #pragma unroll
            for (int c4 = 0; c4 < 4; ++c4) {
                uintx4 v = (c4 == 0) ? v0 : (c4 == 1) ? v1 : (c4 == 2) ? v2 : v3;
                int byte = srow * (KTOT * 2) + sseg * 64 + c4 * 16;
                *reinterpret_cast<uintx4*>(lds + (byte ^ sswz)) = v;
            }
        }
        __syncthreads();

        // ---- MFMA: preact[16 x 32] for gate w, K = 640 ----
        floatx4 acc0 = {0.f, 0.f, 0.f, 0.f}, acc1 = {0.f, 0.f, 0.f, 0.f};
        #pragma unroll
        for (int ks = 0; ks < 20; ++ks) {
            int byte = (abase + ks * 64) ^ aswz;
            short8 a = *reinterpret_cast<const short8*>(lds + byte);
            acc0 = __builtin_amdgcn_mfma_f32_16x16x32_bf16(a, bfr0[ks], acc0, 0, 0, 0);
            acc1 = __builtin_amdgcn_mfma_f32_16x16x32_bf16(a, bfr1[ks], acc1, 0, 0, 0);
        }
        // C layout: col = lane&15, row = (lane>>4)*4 + r  (m89-verified)
        #pragma unroll
        for (int r = 0; r < 4; ++r) {
            pre[w][(lane >> 4) * 4 + r][(lane & 15)]      = acc0[r];
            pre[w][(lane >> 4) * 4 + r][16 + (lane & 15)] = acc1[r];
        }
        __syncthreads();

        // ---- elementwise LSTM cell; c-state lives in regs ----
        float hp[2];
        #pragma unroll
        for (int e = 0; e < 2; ++e) {
            int col = epr * 2 + e;
            float ag = pre[0][erow][col] + bge[e];
            float ai = pre[1][erow][col] + bie[e];
            float af = pre[2][erow][col] + bfe[e];
            float ao = pre[3][erow][col] + boe[e];
            float g = tanhf_(ag), ii = sigf(ai), f = sigf(af), o = sigf(ao);
            float c = g * ii + cst[e] * f;
            cst[e] = c;
            hp[e] = tanhf_(c) * o;
        }
        uint32_t packed = (uint32_t)f2bf(hp[0]) | ((uint32_t)f2bf(hp[1]) << 16);
        uint32_t* hdst = reinterpret_cast<uint32_t*>(
            hbuf + (size_t)((t + 1) & 1) * B_ * H_ + (size_t)(b0 + erow) * H_ + hcg0);
        __hip_atomic_store(hdst, packed, __ATOMIC_RELAXED, __HIP_MEMORY_SCOPE_AGENT);
        // drain own h stores to the device coherence point, then signal
        asm volatile("s_waitcnt vmcnt(0)" ::: "memory");
        __syncthreads();   // all threads past their waitcnt -> all h stores at MALL
        if (tid == 0)
            __hip_atomic_store(fbase + cg * 16, t + 1, __ATOMIC_RELAXED,
                               __HIP_MEMORY_SCOPE_AGENT);
        // next iteration's wait-barrier protects hx from early overwrite
    }
}

// ---- final projection: out[b][c] = h_T[b] . wph[:,c] + bp[c] ----
__global__ void k_proj(const uint16_t* __restrict__ hb0, const float* __restrict__ wph,
                       const float* __restrict__ bp, float* __restrict__ out) {
    int b = blockIdx.x, lane = threadIdx.x;     // 64 threads
    const uint32_t* hrow = reinterpret_cast<const uint32_t*>(hb0 + (size_t)b * H_);
    float p[C_];
    #pragma unroll
    for (int c = 0; c < C_; ++c) p[c] = 0.f;
    #pragma unroll
    for (int q = 0; q < 4; ++q) {
        int k2 = lane + q * 64;                 // uint32 index 0..255 -> elems 2k2, 2k2+1
        uint32_t u = __hip_atomic_load(hrow + k2, __ATOMIC_RELAXED, __HIP_MEMORY_SCOPE_AGENT);
        float h0 = bf2f((uint16_t)(u & 0xFFFFu));
        float h1 = bf2f((uint16_t)(u >> 16));
        #pragma unroll
        for (int c = 0; c < C_; ++c)
            p[c] += h0 * wph[(size_t)(2 * k2) * C_ + c] + h1 * wph[(size_t)(2 * k2 + 1) * C_ + c];
    }
    #pragma unroll
    for (int c = 0; c < C_; ++c) {
        float v = p[c];
        #pragma unroll
        for (int off = 32; off; off >>= 1) v += __shfl_down(v, off, 64);
        if (lane == 0) out[(size_t)b * C_ + c] = v + bp[c];
    }
}

extern "C" void kernel_launch(void* const* d_in, const int* in_sizes, int n_in,
                              void* d_out, int out_size, void* d_ws, size_t ws_size,
                              hipStream_t stream) {
    const float* x   = (const float*)d_in[0];
    const float* wgx = (const float*)d_in[1];
    const float* wgh = (const float*)d_in[2];
    const float* bg  = (const float*)d_in[3];
    const float* wix = (const float*)d_in[4];
    const float* wih = (const float*)d_in[5];
    const float* bi  = (const float*)d_in[6];
    const float* wfx = (const float*)d_in[7];
    const float* wfh = (const float*)d_in[8];
    const float* bf  = (const float*)d_in[9];
    const float* wox = (const float*)d_in[10];
    const float* woh = (const float*)d_in[11];
    const float* bo  = (const float*)d_in[12];
    const float* wph = (const float*)d_in[13];
    const float* bp  = (const float*)d_in[14];

    if (ws_size < WS_NEED) return;  // fail loud (wrong output) rather than corrupt

    char* ws = (char*)d_ws;
    uint16_t* xbp = (uint16_t*)(ws + OFF_XB);
    uint16_t* wcp = (uint16_t*)(ws + OFF_WC);
    uint16_t* hbp = (uint16_t*)(ws + OFF_HB);
    int*      flp = (int*)(ws + OFF_FL);

    hipMemsetAsync(flp, 0, SZ_FL, stream);
    k_cvt_x<<<(B_ * T_ * D_) / (256 * 4), 256, 0, stream>>>(x, xbp);
    k_build_w<<<4 * H_, 256, 0, stream>>>(wgh, wih, wfh, woh, wgx, wix, wfx, wox, wcp);
    k_lstm<<<256, 256, 0, stream>>>(xbp, wcp, bg, bi, bf, bo, hbp, flp);
    k_proj<<<B_, 64, 0, stream>>>(hbp /* parity 0 holds h_T */, wph, bp, (float*)d_out);
}

// Round 14
// 1459.866 us; speedup vs baseline: 2.7759x; 2.7759x over previous
//
#include <hip/hip_runtime.h>
#include <hip/hip_bf16.h>
#include <stdint.h>

typedef __attribute__((ext_vector_type(8))) short short8;
typedef __attribute__((ext_vector_type(4))) short short4v;
typedef __attribute__((ext_vector_type(4))) float floatx4;
typedef __attribute__((ext_vector_type(4))) unsigned int uintx4;
typedef __attribute__((ext_vector_type(4))) unsigned short ushort4v;

#define DEVI __device__ __forceinline__

// ---- problem sizes ----
constexpr int B_ = 256, T_ = 512, D_ = 128, H_ = 512, C_ = 10;
constexpr int KTOT = H_ + D_;       // 640: k = [h(512) ; x(128)]
constexpr int RG = 16;              // batch rows per group
constexpr int NBG = 16;             // batch groups
constexpr int NCG = 8;              // column groups (HCW=64)
constexpr int HCW = 64;             // h-cols per WG
constexpr int NTH = 512;            // 8 waves per WG

// ---- workspace layout (bytes) ----
constexpr size_t OFF_XB = 0;
constexpr size_t SZ_XB  = (size_t)B_ * T_ * D_ * 2;          // x in bf16
constexpr size_t OFF_WC = OFF_XB + SZ_XB;
constexpr size_t SZ_WC  = (size_t)4 * H_ * KTOT * 2;         // Wcomb[4*H][640] bf16
constexpr size_t OFF_HB = OFF_WC + SZ_WC;
constexpr size_t SZ_HB  = (size_t)2 * B_ * H_ * 2;           // h double buffer bf16
constexpr size_t OFF_FL = OFF_HB + SZ_HB;
constexpr size_t SZ_FL  = (size_t)NBG * NCG * 64;            // flags: 64B apart
constexpr size_t WS_NEED = OFF_FL + SZ_FL;

DEVI uint16_t f2bf(float f) {
    uint32_t u = __builtin_bit_cast(uint32_t, f);
    u += 0x7FFFu + ((u >> 16) & 1u);
    return (uint16_t)(u >> 16);
}
DEVI float bf2f(uint16_t u) {
    return __builtin_bit_cast(float, (uint32_t)u << 16);
}
DEVI float sigf(float x)  { return 1.0f / (1.0f + __expf(-x)); }
DEVI float tanhf_(float x){ return 1.0f - 2.0f / (1.0f + __expf(2.0f * x)); }

// ---- prep: x fp32 -> bf16 ----
__global__ void k_cvt_x(const float* __restrict__ x, uint16_t* __restrict__ xb) {
    int i = (blockIdx.x * 256 + threadIdx.x) * 4;   // total B*T*D = 16777216
    float4 v = *reinterpret_cast<const float4*>(x + i);
    ushort4v o;
    o.x = f2bf(v.x); o.y = f2bf(v.y); o.z = f2bf(v.z); o.w = f2bf(v.w);
    *reinterpret_cast<ushort4v*>(xb + i) = o;
}

// ---- prep: build combined transposed bf16 weights Wcomb[n'=g*512+n][k] ----
__global__ void k_build_w(const float* __restrict__ wgh, const float* __restrict__ wih,
                          const float* __restrict__ wfh, const float* __restrict__ woh,
                          const float* __restrict__ wgx, const float* __restrict__ wix,
                          const float* __restrict__ wfx, const float* __restrict__ wox,
                          uint16_t* __restrict__ wc) {
    int np = blockIdx.x;            // 0..2047
    int g = np >> 9, n = np & 511;
    const float* wh = (g == 0) ? wgh : (g == 1) ? wih : (g == 2) ? wfh : woh;
    const float* wx = (g == 0) ? wgx : (g == 1) ? wix : (g == 2) ? wfx : wox;
    for (int k = threadIdx.x; k < KTOT; k += 256) {
        float v = (k < H_) ? wh[(size_t)k * H_ + n] : wx[(size_t)(k - H_) * H_ + n];
        wc[(size_t)np * KTOT + k] = f2bf(v);
    }
}

// Opaque 16B weight load (kept resident in the unified VGPR/AGPR file)
#define WLOAD(dst, base, IMM) \
    asm volatile("global_load_dwordx4 %0, %1, off offset:" #IMM \
                 : "=v"(dst) : "v"(base))
#define WLOAD20(arr, base) \
    WLOAD(arr[0],  base, 0);    WLOAD(arr[1],  base, 64);   \
    WLOAD(arr[2],  base, 128);  WLOAD(arr[3],  base, 192);  \
    WLOAD(arr[4],  base, 256);  WLOAD(arr[5],  base, 320);  \
    WLOAD(arr[6],  base, 384);  WLOAD(arr[7],  base, 448);  \
    WLOAD(arr[8],  base, 512);  WLOAD(arr[9],  base, 576);  \
    WLOAD(arr[10], base, 640);  WLOAD(arr[11], base, 704);  \
    WLOAD(arr[12], base, 768);  WLOAD(arr[13], base, 832);  \
    WLOAD(arr[14], base, 896);  WLOAD(arr[15], base, 960);  \
    WLOAD(arr[16], base, 1024); WLOAD(arr[17], base, 1088); \
    WLOAD(arr[18], base, 1152); WLOAD(arr[19], base, 1216)

// device-coherent 16B load (h exchange)
#define HLOAD(dst, base, IMM) \
    asm volatile("global_load_dwordx4 %0, %1, off offset:" #IMM " sc0 sc1" \
                 : "=v"(dst) : "v"(base) : "memory")

// ---- main recurrent kernel ----
// WG = 16 batch rows x 64 h-cols, EIGHT waves (512 thr). Wave w: gate = w&3,
// col-half = w>>2 (32 cols, 2 B-tiles, 40 MFMA, 160 weight regs -- r8-proven
// per-wave load). 128 WGs total; fan-in 8 flags. Sync = r8-proven semantics:
//   producer: h store (sc1, relaxed) -> vmcnt(0) drain -> barrier -> tid0 flag
//   consumer: wave0 lanes 0-7 poll the 8 per-cg flags in parallel (+ballot)
// Device-coherence-point read traffic halves: 128 WGs x 16 KB = 2 MB/step
// (read/step = 131072/HCW KB -- the measured floor of rounds 6-10).
__global__ __launch_bounds__(NTH, 2) void k_lstm(
    const uint16_t* __restrict__ xb,   // [B][T][D] bf16
    const uint16_t* __restrict__ wc,   // [4H][KTOT] bf16
    const float* __restrict__ bgp, const float* __restrict__ bip,
    const float* __restrict__ bfp, const float* __restrict__ bop,
    uint16_t* hbuf,                    // [2][B][H] bf16
    int* flags)                        // [NBG][NCG] ints, 64B apart
{
    __shared__ __align__(16) char hx[RG * KTOT * 2];              // 20 KB, XOR-swizzled
    __shared__ float pre[4][RG][HCW + 1];                         // [4][16][65], 16.6 KB

    const int tid  = threadIdx.x;
    const int lane = tid & 63;
    const int w    = tid >> 6;          // 0..7
    const int gate = w & 3;
    const int half = w >> 2;            // col half: 0 -> cols 0..31, 1 -> 32..63
    const int bid  = blockIdx.x;        // 0..127
    // keep each batch-group's 8 WGs on one XCD (perf heuristic only)
    const int xcd = bid & 7, j = bid >> 3;      // j 0..15
    const int bg = xcd * 2 + (j >> 3);
    const int cg = j & 7;
    const int b0  = bg * RG;
    const int hc0 = cg * HCW;

    // ---- load this wave's weight slice: 2 col-tiles x 20 ksteps (resident) ----
    short8 bfr0[20], bfr1[20];
    {
        const int lcol = lane & 15, kgrp = lane >> 4;
        const uint16_t* src0 = wc + (size_t)(gate * H_ + hc0 + half * 32 + 0  + lcol) * KTOT + kgrp * 8;
        const uint16_t* src1 = wc + (size_t)(gate * H_ + hc0 + half * 32 + 16 + lcol) * KTOT + kgrp * 8;
        WLOAD20(bfr0, src0);
        WLOAD20(bfr1, src1);
        asm volatile("s_waitcnt vmcnt(0)" ::: "memory");
    }

    // ---- elementwise thread mapping: row = tid>>5, col pair = (tid&31)*2 ----
    const int erow = tid >> 5;          // 0..15
    const int epr  = tid & 31;          // 0..31 -> cols epr*2, epr*2+1
    const int hcg0 = hc0 + epr * 2;
    float bge[2], bie[2], bfe[2], boe[2], cst[2] = {0.f, 0.f};
    #pragma unroll
    for (int e = 0; e < 2; ++e) {
        bge[e] = bgp[hcg0 + e]; bie[e] = bip[hcg0 + e];
        bfe[e] = bfp[hcg0 + e]; boe[e] = bop[hcg0 + e];
    }

    // staging mapping: thread -> (row, 32B h seg + 8B x seg)
    const int srow = tid >> 5, sseg = tid & 31;
    const int sswz = (srow & 7) << 4;
    // A-fragment base (mfma 16x16x32: row = lane&15, k = (lane>>4)*8 + j)
    const int arow = lane & 15, akg = lane >> 4;
    const int abase = arow * (KTOT * 2) + akg * 16;
    const int aswz  = (arow & 7) << 4;

    int* fbase = flags + bg * NCG * 16;   // 16 ints (=64B) per flag slot
    char* lds = (char*)hx;

    for (int t = 0; t < T_; ++t) {
        // ---- stage x part (cols 512..639) BEFORE the wait ----
        {
            const short4v xv = *reinterpret_cast<const short4v*>(
                xb + ((size_t)(b0 + srow) * T_ + t) * D_ + sseg * 4);
            int byte = srow * (KTOT * 2) + H_ * 2 + sseg * 8;
            *reinterpret_cast<short4v*>(lds + (byte ^ sswz)) = xv;
        }

        // ---- wait for h_t from all 8 column groups (parallel flag poll) ----
        if (t > 0) {
            if (w == 0) {
                int it = 0;
                for (;;) {
                    int f = t;
                    if (lane < NCG)
                        f = __hip_atomic_load(fbase + lane * 16, __ATOMIC_RELAXED,
                                              __HIP_MEMORY_SCOPE_AGENT);
                    if (__ballot(f >= t) == ~0ull) break;
                    if (++it > (1 << 22)) break;   // fail loud, not hang
                }
                asm volatile("" ::: "memory");
            }
            __syncthreads();
        }

        // ---- stage h part of A = [h_t ; x_t] into swizzled LDS (32B/thread) ----
        if (t == 0) {
            uintx4 z = {0u, 0u, 0u, 0u};
            #pragma unroll
            for (int c4 = 0; c4 < 2; ++c4) {
                int byte = srow * (KTOT * 2) + sseg * 32 + c4 * 16;
                *reinterpret_cast<uintx4*>(lds + (byte ^ sswz)) = z;
            }
        } else {
            const uint16_t* hsrc = hbuf + (size_t)(t & 1) * B_ * H_
                                        + (size_t)(b0 + srow) * H_ + sseg * 16;
            uintx4 v0, v1;
            HLOAD(v0, hsrc, 0);  HLOAD(v1, hsrc, 16);
            asm volatile("s_waitcnt vmcnt(0)" ::: "memory");
            {
                int byte = srow * (KTOT * 2) + sseg * 32;
                *reinterpret_cast<uintx4*>(lds + (byte ^ sswz)) = v0;
                byte += 16;
                *reinterpret_cast<uintx4*>(lds + (byte ^ sswz)) = v1;
            }
        }
        __syncthreads();

        // ---- MFMA: preact[16 x 32] for (gate, half), K = 640 ----
        floatx4 acc0 = {0.f, 0.f, 0.f, 0.f}, acc1 = {0.f, 0.f, 0.f, 0.f};
        #pragma unroll
        for (int ks = 0; ks < 20; ++ks) {
            int byte = (abase + ks * 64) ^ aswz;
            short8 a = *reinterpret_cast<const short8*>(lds + byte);
            acc0 = __builtin_amdgcn_mfma_f32_16x16x32_bf16(a, bfr0[ks], acc0, 0, 0, 0);
            acc1 = __builtin_amdgcn_mfma_f32_16x16x32_bf16(a, bfr1[ks], acc1, 0, 0, 0);
        }
        // C layout: col = lane&15, row = (lane>>4)*4 + r  (m89-verified)
        #pragma unroll
        for (int r = 0; r < 4; ++r) {
            pre[gate][(lane >> 4) * 4 + r][half * 32 + (lane & 15)]      = acc0[r];
            pre[gate][(lane >> 4) * 4 + r][half * 32 + 16 + (lane & 15)] = acc1[r];
        }
        __syncthreads();

        // ---- elementwise LSTM cell; 2 cols/thread; c-state in regs ----
        float hp[2];
        #pragma unroll
        for (int e = 0; e < 2; ++e) {
            int col = epr * 2 + e;
            float ag = pre[0][erow][col] + bge[e];
            float ai = pre[1][erow][col] + bie[e];
            float af = pre[2][erow][col] + bfe[e];
            float ao = pre[3][erow][col] + boe[e];
            float g = tanhf_(ag), ii = sigf(ai), f = sigf(af), o = sigf(ao);
            float c = g * ii + cst[e] * f;
            cst[e] = c;
            hp[e] = tanhf_(c) * o;
        }
        uint32_t packed = (uint32_t)f2bf(hp[0]) | ((uint32_t)f2bf(hp[1]) << 16);
        uint32_t* hdst = reinterpret_cast<uint32_t*>(
            hbuf + (size_t)((t + 1) & 1) * B_ * H_ + (size_t)(b0 + erow) * H_ + hcg0);
        __hip_atomic_store(hdst, packed, __ATOMIC_RELAXED, __HIP_MEMORY_SCOPE_AGENT);
        // drain own h stores to the device coherence point, then signal
        asm volatile("s_waitcnt vmcnt(0)" ::: "memory");
        __syncthreads();   // all threads past their waitcnt -> all h stores visible
        if (tid == 0)
            __hip_atomic_store(fbase + cg * 16, t + 1, __ATOMIC_RELAXED,
                               __HIP_MEMORY_SCOPE_AGENT);
        // next iteration's wait-barrier protects hx from early overwrite
    }
}

// ---- final projection: out[b][c] = h_T[b] . wph[:,c] + bp[c] ----
__global__ void k_proj(const uint16_t* __restrict__ hb0, const float* __restrict__ wph,
                       const float* __restrict__ bp, float* __restrict__ out) {
    int b = blockIdx.x, lane = threadIdx.x;     // 64 threads
    const uint32_t* hrow = reinterpret_cast<const uint32_t*>(hb0 + (size_t)b * H_);
    float p[C_];
    #pragma unroll
    for (int c = 0; c < C_; ++c) p[c] = 0.f;
    #pragma unroll
    for (int q = 0; q < 4; ++q) {
        int k2 = lane + q * 64;                 // uint32 index 0..255 -> elems 2k2, 2k2+1
        uint32_t u = __hip_atomic_load(hrow + k2, __ATOMIC_RELAXED, __HIP_MEMORY_SCOPE_AGENT);
        float h0 = bf2f((uint16_t)(u & 0xFFFFu));
        float h1 = bf2f((uint16_t)(u >> 16));
        #pragma unroll
        for (int c = 0; c < C_; ++c)
            p[c] += h0 * wph[(size_t)(2 * k2) * C_ + c] + h1 * wph[(size_t)(2 * k2 + 1) * C_ + c];
    }
    #pragma unroll
    for (int c = 0; c < C_; ++c) {
        float v = p[c];
        #pragma unroll
        for (int off = 32; off; off >>= 1) v += __shfl_down(v, off, 64);
        if (lane == 0) out[(size_t)b * C_ + c] = v + bp[c];
    }
}

extern "C" void kernel_launch(void* const* d_in, const int* in_sizes, int n_in,
                              void* d_out, int out_size, void* d_ws, size_t ws_size,
                              hipStream_t stream) {
    const float* x   = (const float*)d_in[0];
    const float* wgx = (const float*)d_in[1];
    const float* wgh = (const float*)d_in[2];
    const float* bg  = (const float*)d_in[3];
    const float* wix = (const float*)d_in[4];
    const float* wih = (const float*)d_in[5];
    const float* bi  = (const float*)d_in[6];
    const float* wfx = (const float*)d_in[7];
    const float* wfh = (const float*)d_in[8];
    const float* bf  = (const float*)d_in[9];
    const float* wox = (const float*)d_in[10];
    const float* woh = (const float*)d_in[11];
    const float* bo  = (const float*)d_in[12];
    const float* wph = (const float*)d_in[13];
    const float* bp  = (const float*)d_in[14];

    if (ws_size < WS_NEED) return;  // fail loud (wrong output) rather than corrupt

    char* ws = (char*)d_ws;
    uint16_t* xbp = (uint16_t*)(ws + OFF_XB);
    uint16_t* wcp = (uint16_t*)(ws + OFF_WC);
    uint16_t* hbp = (uint16_t*)(ws + OFF_HB);
    int*      flp = (int*)(ws + OFF_FL);

    hipMemsetAsync(flp, 0, SZ_FL, stream);
    k_cvt_x<<<(B_ * T_ * D_) / (256 * 4), 256, 0, stream>>>(x, xbp);
    k_build_w<<<4 * H_, 256, 0, stream>>>(wgh, wih, wfh, woh, wgx, wix, wfx, wox, wcp);
    k_lstm<<<NBG * NCG, NTH, 0, stream>>>(xbp, wcp, bg, bi, bf, bo, hbp, flp);
    k_proj<<<B_, 64, 0, stream>>>(hbp /* parity 0 holds h_T */, wph, bp, (float*)d_out);
}